// Round 2
// baseline (28.107 us; speedup 1.0000x reference)
//
#include <hip/hip_runtime.h>

#define N_PATCH (32 * 112 * 112)

__global__ __launch_bounds__(256) void qfeat_kernel(const float* __restrict__ x,
                                                    const float* __restrict__ wts,
                                                    float* __restrict__ out) {
    // 8 gate matrices (2 layers x 4 wires), each 2x2 complex -> 8 floats:
    // [m00r, m00i, m01r, m01i, m10r, m10i, m11r, m11i]
    __shared__ float g[8][8];
    if (threadIdx.x < 8) {
        int gid = threadIdx.x;
        float phi   = wts[gid * 3 + 0];
        float theta = wts[gid * 3 + 1];
        float omega = wts[gid * 3 + 2];
        float st, ct; sincosf(0.5f * theta, &st, &ct);
        float sp, cp; sincosf(-0.5f * (phi + omega), &sp, &cp);   // ep = cp + i sp
        float sm, cm; sincosf(-0.5f * (phi - omega), &sm, &cm);   // em = cm + i sm
        g[gid][0] =  cp * ct;  g[gid][1] =  sp * ct;   // m00 = ep * c
        g[gid][2] = -cm * st;  g[gid][3] =  sm * st;   // m01 = -conj(em) * s
        g[gid][4] =  cm * st;  g[gid][5] =  sm * st;   // m10 = em * s
        g[gid][6] =  cp * ct;  g[gid][7] = -sp * ct;   // m11 = conj(ep) * c
    }
    __syncthreads();

    const int pid = blockIdx.x * 256 + threadIdx.x;   // grid is exact: 1568*256 == N_PATCH

    int j = pid % 112;
    int t = pid / 112;
    int i = t % 112;
    int b = t / 112;

    // patch: wire0 = x[b,2i,2j], wire1 = x[b,2i,2j+1], wire2 = x[b,2i+1,2j], wire3 = x[b,2i+1,2j+1]
    const float2* r0 = reinterpret_cast<const float2*>(x + (((size_t)b * 224 + 2 * i) * 224 + 2 * j));
    const float2* r1 = reinterpret_cast<const float2*>(x + (((size_t)b * 224 + 2 * i + 1) * 224 + 2 * j));
    float2 top = *r0;
    float2 bot = *r1;
    float p[4] = {top.x, top.y, bot.x, bot.y};

    // Encoding: RY(a)RX(a)|0> with a = p*pi, half-angle = p*pi/2 rad = p*0.25 revolutions.
    // v_sin_f32 / v_cos_f32 take revolutions; p in [0,1] -> arg in [0,0.25], no reduction needed.
    // v0 = c^2 + i s^2 ; v1 = s c - i c s
    float vr[4][2], vi[4][2];
#pragma unroll
    for (int w = 0; w < 4; ++w) {
        float rev = p[w] * 0.25f;
        float s = __builtin_amdgcn_sinf(rev);
        float c = __builtin_amdgcn_cosf(rev);
        vr[w][0] = c * c;  vi[w][0] = s * s;
        vr[w][1] = s * c;  vi[w][1] = -c * s;
    }

    // Tensor product, staged: wire0 is MSB of the 4-bit state index.
    float t2r[4], t2i[4];
#pragma unroll
    for (int idx = 0; idx < 4; ++idx) {
        int b0 = idx >> 1, b1 = idx & 1;
        t2r[idx] = vr[0][b0] * vr[1][b1] - vi[0][b0] * vi[1][b1];
        t2i[idx] = vr[0][b0] * vi[1][b1] + vi[0][b0] * vr[1][b1];
    }
    float t3r[8], t3i[8];
#pragma unroll
    for (int idx = 0; idx < 8; ++idx) {
        int hi = idx >> 1, b2 = idx & 1;
        t3r[idx] = t2r[hi] * vr[2][b2] - t2i[hi] * vi[2][b2];
        t3i[idx] = t2r[hi] * vi[2][b2] + t2i[hi] * vr[2][b2];
    }
    float ar[16], ai[16];
#pragma unroll
    for (int idx = 0; idx < 16; ++idx) {
        int hi = idx >> 1, b3 = idx & 1;
        ar[idx] = t3r[hi] * vr[3][b3] - t3i[hi] * vi[3][b3];
        ai[idx] = t3r[hi] * vi[3][b3] + t3i[hi] * vr[3][b3];
    }

    // 2 StronglyEntanglingLayers: Rot on each wire, then ring of CNOTs (r=1, then r=2).
    // CNOT swap loops are compile-time register renames (free after unroll).
#pragma unroll
    for (int l = 0; l < 2; ++l) {
#pragma unroll
        for (int w = 0; w < 4; ++w) {
            const float* gm = g[l * 4 + w];
            float m00r = gm[0], m00i = gm[1], m01r = gm[2], m01i = gm[3];
            float m10r = gm[4], m10i = gm[5], m11r = gm[6], m11i = gm[7];
            const int mask = 8 >> w;
#pragma unroll
            for (int idx = 0; idx < 16; ++idx) {
                if (idx & mask) continue;
                const int k = idx | mask;
                float a0r = ar[idx], a0i = ai[idx];
                float a1r = ar[k],   a1i = ai[k];
                ar[idx] = m00r * a0r - m00i * a0i + m01r * a1r - m01i * a1i;
                ai[idx] = m00r * a0i + m00i * a0r + m01r * a1i + m01i * a1r;
                ar[k]   = m10r * a0r - m10i * a0i + m11r * a1r - m11i * a1i;
                ai[k]   = m10r * a0i + m10i * a0r + m11r * a1i + m11i * a1r;
            }
        }
        const int r = (l == 0) ? 1 : 2;
#pragma unroll
        for (int w = 0; w < 4; ++w) {
            const int mc = 8 >> w;
            const int mt = 8 >> ((w + r) & 3);
#pragma unroll
            for (int idx = 0; idx < 16; ++idx) {
                if ((idx & mc) && !(idx & mt)) {
                    const int k = idx | mt;
                    float tr = ar[idx]; ar[idx] = ar[k]; ar[k] = tr;
                    float ti = ai[idx]; ai[idx] = ai[k]; ai[k] = ti;
                }
            }
        }
    }

    // PauliZ expvals: wire w sign flips when bit (8>>w) set
    float o0 = 0.f, o1 = 0.f, o2 = 0.f, o3 = 0.f;
#pragma unroll
    for (int idx = 0; idx < 16; ++idx) {
        float pb = ar[idx] * ar[idx] + ai[idx] * ai[idx];
        o0 += (idx & 8) ? -pb : pb;
        o1 += (idx & 4) ? -pb : pb;
        o2 += (idx & 2) ? -pb : pb;
        o3 += (idx & 1) ? -pb : pb;
    }

    *reinterpret_cast<float4*>(out + (size_t)pid * 4) = make_float4(o0, o1, o2, o3);
}

extern "C" void kernel_launch(void* const* d_in, const int* in_sizes, int n_in,
                              void* d_out, int out_size, void* d_ws, size_t ws_size,
                              hipStream_t stream) {
    const float* x   = (const float*)d_in[0];
    const float* wts = (const float*)d_in[1];
    float* out       = (float*)d_out;
    const int nblocks = N_PATCH / 256;   // exact
    qfeat_kernel<<<nblocks, 256, 0, stream>>>(x, wts, out);
}

// Round 3
// 24.539 us; speedup vs baseline: 1.1454x; 1.1454x over previous
//
#include <hip/hip_runtime.h>

#define N_PATCH (32 * 112 * 112)

// ---------------- Kernel 1: build the 8 Rot matrices (2 layers x 4 wires) ----------------
// Each matrix is 2x2 complex -> 8 floats: [m00r,m00i, m01r,m01i, m10r,m10i, m11r,m11i]
__global__ void qgates_kernel(const float* __restrict__ wts, float* __restrict__ g) {
    int gid = threadIdx.x;
    if (gid >= 8) return;
    float phi   = wts[gid * 3 + 0];
    float theta = wts[gid * 3 + 1];
    float omega = wts[gid * 3 + 2];
    float st, ct; sincosf(0.5f * theta, &st, &ct);
    float sp, cp; sincosf(-0.5f * (phi + omega), &sp, &cp);   // ep = cp + i sp
    float sm, cm; sincosf(-0.5f * (phi - omega), &sm, &cm);   // em = cm + i sm
    g[gid * 8 + 0] =  cp * ct;  g[gid * 8 + 1] =  sp * ct;    // m00 = ep * c
    g[gid * 8 + 2] = -cm * st;  g[gid * 8 + 3] =  sm * st;    // m01 = -conj(em) * s
    g[gid * 8 + 4] =  cm * st;  g[gid * 8 + 5] =  sm * st;    // m10 = em * s
    g[gid * 8 + 6] =  cp * ct;  g[gid * 8 + 7] = -sp * ct;    // m11 = conj(ep) * c
}

// ---------------- Kernel 2: per-patch circuit simulation ----------------
// Gate matrices arrive via uniform constant-offset loads -> SGPRs (s_load),
// costing zero VGPRs. Layer-1 Rots are folded into the per-wire 2-vectors
// before the tensor product (16 FMA/wire instead of 128).
__global__ __launch_bounds__(256) void qfeat_kernel(const float* __restrict__ x,
                                                    const float* __restrict__ g,
                                                    float* __restrict__ out) {
    const int pid = blockIdx.x * 256 + threadIdx.x;   // grid exact: 1568*256 == N_PATCH

    int j = pid % 112;
    int t = pid / 112;
    int i = t % 112;
    int b = t / 112;

    // patch: wire0 = x[b,2i,2j], wire1 = x[b,2i,2j+1], wire2 = x[b,2i+1,2j], wire3 = x[b,2i+1,2j+1]
    const float2 top = *reinterpret_cast<const float2*>(x + (((size_t)b * 224 + 2 * i) * 224 + 2 * j));
    const float2 bot = *reinterpret_cast<const float2*>(x + (((size_t)b * 224 + 2 * i + 1) * 224 + 2 * j));
    float p[4] = {top.x, top.y, bot.x, bot.y};

    // Encoding state per wire: v0 = c^2 + i s^2, v1 = sc - i cs with c=cos(pi p/2), s=sin(pi p/2).
    // Double angle: C=cos(pi p), S=sin(pi p): c^2=(1+C)/2, s^2=(1-C)/2, sc=S/2.
    // hw sin/cos take revolutions: pi*p rad = p*0.5 rev, p in [0,1] -> no range reduction needed.
    // Immediately apply the layer-1 Rot for this wire (2x2 complex mat-vec).
    float ur[4][2], ui[4][2];
#pragma unroll
    for (int w = 0; w < 4; ++w) {
        float S = __builtin_amdgcn_sinf(p[w] * 0.5f);
        float C = __builtin_amdgcn_cosf(p[w] * 0.5f);
        float v0r = 0.5f * (1.0f + C), v0i = 0.5f * (1.0f - C);
        float v1r = 0.5f * S,          v1i = -0.5f * S;
        const float* m = g + w * 8;   // layer-1 Rot, uniform -> SGPR
        ur[w][0] = m[0] * v0r - m[1] * v0i + m[2] * v1r - m[3] * v1i;
        ui[w][0] = m[0] * v0i + m[1] * v0r + m[2] * v1i + m[3] * v1r;
        ur[w][1] = m[4] * v0r - m[5] * v0i + m[6] * v1r - m[7] * v1i;
        ui[w][1] = m[4] * v0i + m[5] * v0r + m[6] * v1i + m[7] * v1r;
    }

    // Tensor product (wire0 = MSB of the 4-bit state index).
    float t2r[4], t2i[4];
#pragma unroll
    for (int idx = 0; idx < 4; ++idx) {
        int b0 = idx >> 1, b1 = idx & 1;
        t2r[idx] = ur[0][b0] * ur[1][b1] - ui[0][b0] * ui[1][b1];
        t2i[idx] = ur[0][b0] * ui[1][b1] + ui[0][b0] * ur[1][b1];
    }
    float t3r[8], t3i[8];
#pragma unroll
    for (int idx = 0; idx < 8; ++idx) {
        int hi = idx >> 1, b2 = idx & 1;
        t3r[idx] = t2r[hi] * ur[2][b2] - t2i[hi] * ui[2][b2];
        t3i[idx] = t2r[hi] * ui[2][b2] + t2i[hi] * ur[2][b2];
    }
    float ar[16], ai[16];
#pragma unroll
    for (int idx = 0; idx < 16; ++idx) {
        int hi = idx >> 1, b3 = idx & 1;
        ar[idx] = t3r[hi] * ur[3][b3] - t3i[hi] * ui[3][b3];
        ai[idx] = t3r[hi] * ui[3][b3] + t3i[hi] * ur[3][b3];
    }

    // CNOT ring, r=1: CNOT(w, (w+1)%4) for w=0..3 (register renames, free after unroll).
#pragma unroll
    for (int w = 0; w < 4; ++w) {
        const int mc = 8 >> w;
        const int mt = 8 >> ((w + 1) & 3);
#pragma unroll
        for (int idx = 0; idx < 16; ++idx) {
            if ((idx & mc) && !(idx & mt)) {
                const int k = idx | mt;
                float tr = ar[idx]; ar[idx] = ar[k]; ar[k] = tr;
                float ti = ai[idx]; ai[idx] = ai[k]; ai[k] = ti;
            }
        }
    }

    // Layer-2 Rot on each wire (matrix elements in SGPRs).
#pragma unroll
    for (int w = 0; w < 4; ++w) {
        const float* gm = g + (4 + w) * 8;
        float m00r = gm[0], m00i = gm[1], m01r = gm[2], m01i = gm[3];
        float m10r = gm[4], m10i = gm[5], m11r = gm[6], m11i = gm[7];
        const int mask = 8 >> w;
#pragma unroll
        for (int idx = 0; idx < 16; ++idx) {
            if (idx & mask) continue;
            const int k = idx | mask;
            float a0r = ar[idx], a0i = ai[idx];
            float a1r = ar[k],   a1i = ai[k];
            ar[idx] = m00r * a0r - m00i * a0i + m01r * a1r - m01i * a1i;
            ai[idx] = m00r * a0i + m00i * a0r + m01r * a1i + m01i * a1r;
            ar[k]   = m10r * a0r - m10i * a0i + m11r * a1r - m11i * a1i;
            ai[k]   = m10r * a0i + m10i * a0r + m11r * a1i + m11i * a1r;
        }
    }

    // CNOT ring, r=2: CNOT(w, (w+2)%4).
#pragma unroll
    for (int w = 0; w < 4; ++w) {
        const int mc = 8 >> w;
        const int mt = 8 >> ((w + 2) & 3);
#pragma unroll
        for (int idx = 0; idx < 16; ++idx) {
            if ((idx & mc) && !(idx & mt)) {
                const int k = idx | mt;
                float tr = ar[idx]; ar[idx] = ar[k]; ar[k] = tr;
                float ti = ai[idx]; ai[idx] = ai[k]; ai[k] = ti;
            }
        }
    }

    // PauliZ expvals: wire w sign flips when bit (8>>w) set.
    float o0 = 0.f, o1 = 0.f, o2 = 0.f, o3 = 0.f;
#pragma unroll
    for (int idx = 0; idx < 16; ++idx) {
        float pb = ar[idx] * ar[idx] + ai[idx] * ai[idx];
        o0 += (idx & 8) ? -pb : pb;
        o1 += (idx & 4) ? -pb : pb;
        o2 += (idx & 2) ? -pb : pb;
        o3 += (idx & 1) ? -pb : pb;
    }

    *reinterpret_cast<float4*>(out + (size_t)pid * 4) = make_float4(o0, o1, o2, o3);
}

extern "C" void kernel_launch(void* const* d_in, const int* in_sizes, int n_in,
                              void* d_out, int out_size, void* d_ws, size_t ws_size,
                              hipStream_t stream) {
    const float* x   = (const float*)d_in[0];
    const float* wts = (const float*)d_in[1];
    float* out       = (float*)d_out;
    float* gmat      = (float*)d_ws;   // 64 floats

    qgates_kernel<<<1, 64, 0, stream>>>(wts, gmat);
    qfeat_kernel<<<N_PATCH / 256, 256, 0, stream>>>(x, gmat, out);
}

// Round 4
// 15.789 us; speedup vs baseline: 1.7802x; 1.5542x over previous
//
#include <hip/hip_runtime.h>

#define N_PATCH (32 * 112 * 112)

// Single fused kernel: threads 0-7 build the 8 Rot matrices (2 layers x 4 wires)
// into LDS, then every thread simulates one 2x2-patch 4-qubit circuit in registers.
// Gate layout per gate: [m00r,m00i, m01r,m01i, m10r,m10i, m11r,m11i]
__global__ __launch_bounds__(256) void qfeat_kernel(const float* __restrict__ x,
                                                    const float* __restrict__ wts,
                                                    float* __restrict__ out) {
    __shared__ __align__(16) float g[64];
    if (threadIdx.x < 8) {
        const int gid = threadIdx.x;
        float phi   = wts[gid * 3 + 0];
        float theta = wts[gid * 3 + 1];
        float omega = wts[gid * 3 + 2];
        float st, ct; sincosf(0.5f * theta, &st, &ct);
        float sp, cp; sincosf(-0.5f * (phi + omega), &sp, &cp);   // ep = cp + i sp
        float sm, cm; sincosf(-0.5f * (phi - omega), &sm, &cm);   // em = cm + i sm
        g[gid * 8 + 0] =  cp * ct;  g[gid * 8 + 1] =  sp * ct;   // m00 = ep * c
        g[gid * 8 + 2] = -cm * st;  g[gid * 8 + 3] =  sm * st;   // m01 = -conj(em) * s
        g[gid * 8 + 4] =  cm * st;  g[gid * 8 + 5] =  sm * st;   // m10 = em * s
        g[gid * 8 + 6] =  cp * ct;  g[gid * 8 + 7] = -sp * ct;   // m11 = conj(ep) * c
    }
    __syncthreads();

    const int pid = blockIdx.x * 256 + threadIdx.x;   // grid exact: 1568*256 == N_PATCH

    int j = pid % 112;
    int t = pid / 112;
    int i = t % 112;
    int b = t / 112;

    // patch: wire0 = x[b,2i,2j], wire1 = x[b,2i,2j+1], wire2 = x[b,2i+1,2j], wire3 = x[b,2i+1,2j+1]
    const float2 top = *reinterpret_cast<const float2*>(x + (((size_t)b * 224 + 2 * i) * 224 + 2 * j));
    const float2 bot = *reinterpret_cast<const float2*>(x + (((size_t)b * 224 + 2 * i + 1) * 224 + 2 * j));
    float p[4] = {top.x, top.y, bot.x, bot.y};

    // Per-wire encoded state v0 = c^2 + i s^2, v1 = sc - i cs (c=cos(pi p/2), s=sin(pi p/2)),
    // via double angle C=cos(pi p), S=sin(pi p). hw sin/cos take revolutions: pi*p rad = 0.5*p rev,
    // p in [0,1] so no range reduction. Layer-1 Rot folded in immediately (16 FMA vs 128).
    float ur[4][2], ui[4][2];
#pragma unroll
    for (int w = 0; w < 4; ++w) {
        float S = __builtin_amdgcn_sinf(p[w] * 0.5f);
        float C = __builtin_amdgcn_cosf(p[w] * 0.5f);
        float v0r = 0.5f * (1.0f + C), v0i = 0.5f * (1.0f - C);
        float v1r = 0.5f * S,          v1i = -0.5f * S;
        const float* m = g + w * 8;   // LDS broadcast (uniform addr, conflict-free)
        ur[w][0] = m[0] * v0r - m[1] * v0i + m[2] * v1r - m[3] * v1i;
        ui[w][0] = m[0] * v0i + m[1] * v0r + m[2] * v1i + m[3] * v1r;
        ur[w][1] = m[4] * v0r - m[5] * v0i + m[6] * v1r - m[7] * v1i;
        ui[w][1] = m[4] * v0i + m[5] * v0r + m[6] * v1i + m[7] * v1r;
    }

    // Tensor product (wire0 = MSB of the 4-bit state index).
    float t2r[4], t2i[4];
#pragma unroll
    for (int idx = 0; idx < 4; ++idx) {
        int b0 = idx >> 1, b1 = idx & 1;
        t2r[idx] = ur[0][b0] * ur[1][b1] - ui[0][b0] * ui[1][b1];
        t2i[idx] = ur[0][b0] * ui[1][b1] + ui[0][b0] * ur[1][b1];
    }
    float t3r[8], t3i[8];
#pragma unroll
    for (int idx = 0; idx < 8; ++idx) {
        int hi = idx >> 1, b2 = idx & 1;
        t3r[idx] = t2r[hi] * ur[2][b2] - t2i[hi] * ui[2][b2];
        t3i[idx] = t2r[hi] * ui[2][b2] + t2i[hi] * ur[2][b2];
    }
    float ar[16], ai[16];
#pragma unroll
    for (int idx = 0; idx < 16; ++idx) {
        int hi = idx >> 1, b3 = idx & 1;
        ar[idx] = t3r[hi] * ur[3][b3] - t3i[hi] * ui[3][b3];
        ai[idx] = t3r[hi] * ui[3][b3] + t3i[hi] * ur[3][b3];
    }

    // CNOT ring, r=1: CNOT(w,(w+1)%4) — compile-time register renames (free).
#pragma unroll
    for (int w = 0; w < 4; ++w) {
        const int mc = 8 >> w;
        const int mt = 8 >> ((w + 1) & 3);
#pragma unroll
        for (int idx = 0; idx < 16; ++idx) {
            if ((idx & mc) && !(idx & mt)) {
                const int k = idx | mt;
                float tr = ar[idx]; ar[idx] = ar[k]; ar[k] = tr;
                float ti = ai[idx]; ai[idx] = ai[k]; ai[k] = ti;
            }
        }
    }

    // Layer-2 Rot per wire; gate floats read from LDS right at use (short liveness).
#pragma unroll
    for (int w = 0; w < 4; ++w) {
        const float* gm = g + (4 + w) * 8;
        float m00r = gm[0], m00i = gm[1], m01r = gm[2], m01i = gm[3];
        float m10r = gm[4], m10i = gm[5], m11r = gm[6], m11i = gm[7];
        const int mask = 8 >> w;
#pragma unroll
        for (int idx = 0; idx < 16; ++idx) {
            if (idx & mask) continue;
            const int k = idx | mask;
            float a0r = ar[idx], a0i = ai[idx];
            float a1r = ar[k],   a1i = ai[k];
            ar[idx] = m00r * a0r - m00i * a0i + m01r * a1r - m01i * a1i;
            ai[idx] = m00r * a0i + m00i * a0r + m01r * a1i + m01i * a1r;
            ar[k]   = m10r * a0r - m10i * a0i + m11r * a1r - m11i * a1i;
            ai[k]   = m10r * a0i + m10i * a0r + m11r * a1i + m11i * a1r;
        }
    }

    // CNOT ring, r=2: CNOT(w,(w+2)%4).
#pragma unroll
    for (int w = 0; w < 4; ++w) {
        const int mc = 8 >> w;
        const int mt = 8 >> ((w + 2) & 3);
#pragma unroll
        for (int idx = 0; idx < 16; ++idx) {
            if ((idx & mc) && !(idx & mt)) {
                const int k = idx | mt;
                float tr = ar[idx]; ar[idx] = ar[k]; ar[k] = tr;
                float ti = ai[idx]; ai[idx] = ai[k]; ai[k] = ti;
            }
        }
    }

    // |a|^2 then Walsh-style partial-sum tree: only 4 of 16 WHT outputs needed.
    // bit0(LSB)=wire3, bit1=wire2, bit2=wire1, bit3(MSB)=wire0.
    float pb[16];
#pragma unroll
    for (int idx = 0; idx < 16; ++idx)
        pb[idx] = ar[idx] * ar[idx] + ai[idx] * ai[idx];

    float sA[8], dA[8];
#pragma unroll
    for (int k = 0; k < 8; ++k) { sA[k] = pb[2*k] + pb[2*k+1]; dA[k] = pb[2*k] - pb[2*k+1]; }
    float o3 = ((dA[0] + dA[1]) + (dA[2] + dA[3])) + ((dA[4] + dA[5]) + (dA[6] + dA[7]));

    float sB[4], dB[4];
#pragma unroll
    for (int k = 0; k < 4; ++k) { sB[k] = sA[2*k] + sA[2*k+1]; dB[k] = sA[2*k] - sA[2*k+1]; }
    float o2 = (dB[0] + dB[1]) + (dB[2] + dB[3]);

    float sC0 = sB[0] + sB[1], sC1 = sB[2] + sB[3];
    float dC0 = sB[0] - sB[1], dC1 = sB[2] - sB[3];
    float o1 = dC0 + dC1;
    float o0 = sC0 - sC1;

    *reinterpret_cast<float4*>(out + (size_t)pid * 4) = make_float4(o0, o1, o2, o3);
}

extern "C" void kernel_launch(void* const* d_in, const int* in_sizes, int n_in,
                              void* d_out, int out_size, void* d_ws, size_t ws_size,
                              hipStream_t stream) {
    const float* x   = (const float*)d_in[0];
    const float* wts = (const float*)d_in[1];
    float* out       = (float*)d_out;
    qfeat_kernel<<<N_PATCH / 256, 256, 0, stream>>>(x, wts, out);
}